// Round 12
// baseline (190.389 us; speedup 1.0000x reference)
//
#include <hip/hip_runtime.h>

// ALSTM: adaptive-computation-time LSTM.
//  - sum(w)==1  =>  output = (w@H)@W_out^T + b_out ; only hbar/cbar needed.
//  - steps after halting have w==0 and cannot affect n => early exit exact
//    (b_halt=1 => p0~0.73, halts at t=1: only 2 of 101 steps run).
// R11 post-mortem: all register-load streams cap at ~4 loads in flight/wave
// (compiler waitcnt + VGPR landing zones) -> ~13 GB/s/CU invariant across
// R3-R11. R12: async DMA streams -- global_load_lds into per-wave private
// LDS double-buffers with explicit asm vmcnt(N) waits the compiler can't
// defeat (it cannot see the DMA->LDS dependency). fp32 exact (bf16 dropped).

#define HID    2048
#define INS    1024
#define OUTS   1024
#define MSTEPS 100
#define NBLK   256
#define NTHR   512
#define NWAVE  8
#define JPB    8        // hidden units owned per block
#define RPB    32       // gate rows per block (4 gates * JPB)
#define SLOTF  16       // floats per sync slot (64 B)
#define STGF   1280     // floats per stage buffer (5 KB)
#define WIH_TOT 8396800ULL   // 8192*1025 floats in W_ih

typedef unsigned long long u64;
typedef unsigned int u32;

#define AS1 __attribute__((address_space(1)))
#define AS3 __attribute__((address_space(3)))

// Async global->LDS DMA: 64 lanes x 16 B; LDS dest = uniform base + lane*16.
__device__ __forceinline__ void dma16(const float* g, float* l) {
    __builtin_amdgcn_global_load_lds((AS1 float*)(uintptr_t)g,
                                     (AS3 float*)(u32)(uintptr_t)l, 16, 0, 0);
}
#define WAITV(n)  asm volatile("s_waitcnt vmcnt(" #n ")" ::: "memory")
#define WAITLGKM() asm volatile("s_waitcnt lgkmcnt(0)" ::: "memory")

__device__ __forceinline__ float wave_allreduce(float v) {
    #pragma unroll
    for (int off = 32; off > 0; off >>= 1)
        v += __shfl_xor(v, off, 64);
    return v;
}

__device__ __forceinline__ u64 pack_tag(unsigned tag, float v) {
    return ((u64)tag << 32) | (u64)__float_as_uint(v);
}
__device__ __forceinline__ u64 aload(const u64* p) {
    return __hip_atomic_load(p, __ATOMIC_RELAXED, __HIP_MEMORY_SCOPE_AGENT);
}
__device__ __forceinline__ void astore(u64* p, u64 v) {
    __hip_atomic_store(p, v, __ATOMIC_RELAXED, __HIP_MEMORY_SCOPE_AGENT);
}

// ws layout (floats): [0..4096) arrive slots (256x64B) | [4096..8192)
// mailboxes | [8192..10240) hbuf0 | [10240..12288) hbuf1 | [12288..14336)
// hbar_g.  kernel_launch zeroes the first 32768 bytes each call.

__global__ __launch_bounds__(NTHR) void alstm_kernel(
    const float* __restrict__ x,      const float* __restrict__ h0,
    const float* __restrict__ c0,     const float* __restrict__ W_ih,
    const float* __restrict__ b_ih,   const float* __restrict__ W_hh,
    const float* __restrict__ b_hh,   const float* __restrict__ w_halt,
    const float* __restrict__ b_halt, const float* __restrict__ W_out,
    const float* __restrict__ b_out,  float* __restrict__ out,
    float* __restrict__ ws)
{
    const int b    = blockIdx.x;
    const int tid  = threadIdx.x;
    const int wave = tid >> 6;
    const int lane = tid & 63;

    float* arrive = ws;
    float* mail   = ws + NBLK * SLOTF;
    float* hbuf0  = ws + 2 * NBLK * SLOTF;
    float* hbuf1  = hbuf0 + HID;
    float* hbar_g = hbuf0 + 2 * HID;

    __shared__ __align__(16) float stage[NWAVE][2][STGF];  // 80 KB
    __shared__ __align__(16) float x_lds[INS];             // 4 KB
    __shared__ __align__(16) float h_lds[HID];             // 8 KB
    __shared__ float gate_lds[RPB];
    __shared__ float ihx_lds[RPB];
    __shared__ float wflag_lds[RPB];
    __shared__ float red_lds[4];
    __shared__ float bcast_lds;
    __shared__ float psum[NWAVE];

    const float bh = b_halt[0];
    const int j_own = b * JPB + tid;      // valid when tid < JPB

    const int lr0   = 4 * wave;                              // local rows lr0..+3
    const int rbase = (lr0 >> 3) * HID + b * JPB + (lr0 & 7);

    #define SYNC_ROUND(tag_, part_, dot_) do {                                 \
        if (tid == 0) {                                                        \
            __threadfence();                                                   \
            astore((u64*)(arrive + SLOTF * b), pack_tag((tag_), (part_)));     \
        }                                                                      \
        if (b == 0) {                                                          \
            float pf = 0.f;                                                    \
            if (tid < NBLK) {                                                  \
                u64 v;                                                         \
                do { v = aload((u64*)(arrive + SLOTF * tid)); }                \
                while ((unsigned)(v >> 32) != (unsigned)(tag_));               \
                pf = __uint_as_float((unsigned)v);                             \
            }                                                                  \
            float s = wave_allreduce(pf);                                      \
            if (lane == 0 && wave < 4) red_lds[wave] = s;                      \
            __syncthreads();                                                   \
            if (tid == 0)                                                      \
                bcast_lds = red_lds[0] + red_lds[1] + red_lds[2] + red_lds[3]; \
            __syncthreads();                                                   \
            if (tid < NBLK)                                                    \
                astore((u64*)(mail + SLOTF * tid), pack_tag((tag_), bcast_lds)); \
        }                                                                      \
        if (tid == 0) {                                                        \
            u64 v;                                                             \
            do { v = aload((u64*)(mail + SLOTF * b)); }                        \
            while ((unsigned)(v >> 32) != (unsigned)(tag_));                   \
            bcast_lds = __uint_as_float((unsigned)v);                          \
            __threadfence();                                                   \
        }                                                                      \
        __syncthreads();                                                       \
        (dot_) = bcast_lds;                                                    \
    } while (0)

    // ------------- prologue: stage x; preload biases/c0 -------------
    ((float2*)x_lds)[tid] = ((const float2*)x)[tid];
    float bsum = 0.f, wflg = 0.f;
    if (lane < 4) {
        const int lr = lr0 + lane;
        const int r  = (lr >> 3) * HID + b * JPB + (lr & 7);
        bsum = b_ih[r] + b_hh[r];
        wflg = W_ih[(size_t)r * 1025];
    }
    float c_reg = 0.f, h_reg = 0.f, hbar = 0.f, cbar = 0.f;
    if (tid < JPB) c_reg = c0[j_own];
    __syncthreads();   // x_lds ready; vmcnt drained to 0 baseline

    // ---- W_ih stream: 4 rows/wave via aligned 5KB covers, DMA pipelined ----
    {
        size_t pp[4]; u32 dd[4]; const float* cov[4]; int oob[4];
        #pragma unroll
        for (int rr = 0; rr < 4; ++rr) {
            const int lr = lr0 + rr;
            const int r  = (lr >> 3) * HID + b * JPB + (lr & 7);
            size_t p = (size_t)r * 1025 + 1;        // payload start (floats)
            size_t a = p & ~(size_t)3;              // 16B-aligned cover start
            pp[rr] = p; dd[rr] = (u32)(p - a);
            cov[rr] = W_ih + a;
            oob[rr] = (a + STGF > WIH_TOT);         // only row 8191
        }
        #define IH_ISSUE(rr_) do {                                             \
            const float* ga = cov[rr_] + 4 * lane;                             \
            float* lb = &stage[wave][(rr_) & 1][0];                            \
            dma16(ga,        lb);                                              \
            dma16(ga +  256, lb +  256);                                       \
            dma16(ga +  512, lb +  512);                                       \
            dma16(ga +  768, lb +  768);                                       \
            dma16(oob[rr_] ? cov[rr_] + 4 * lane : ga + 1024, lb + 1024);      \
        } while (0)
        #define IH_CONS(rr_, accv_) do {                                       \
            float* sbuf = &stage[wave][(rr_) & 1][0];                          \
            const u32 d = dd[rr_];                                             \
            if (oob[rr_] && lane < (int)d) {  /* patch garbage tail */         \
                int k = 1024 - (int)d + lane;                                  \
                sbuf[d + k] = W_ih[pp[rr_] + k];                               \
            }                                                                  \
            float acc = 0.f;                                                   \
            _Pragma("unroll")                                                  \
            for (int m = 0; m < 4; ++m) {                                      \
                int k4 = lane + 64 * m; int k = 4 * k4;                        \
                float4 x4 = ((const float4*)x_lds)[k4];                        \
                acc += sbuf[d + k]     * x4.x + sbuf[d + k + 1] * x4.y         \
                     + sbuf[d + k + 2] * x4.z + sbuf[d + k + 3] * x4.w;        \
            }                                                                  \
            (accv_) = acc;                                                     \
        } while (0)
        float i0, i1, i2, i3;
        IH_ISSUE(0); IH_ISSUE(1);
        WAITV(5); IH_CONS(0, i0); WAITLGKM(); IH_ISSUE(2);
        WAITV(5); IH_CONS(1, i1); WAITLGKM(); IH_ISSUE(3);
        WAITV(5); IH_CONS(2, i2);
        WAITV(0); IH_CONS(3, i3);
        i0 = wave_allreduce(i0); i1 = wave_allreduce(i1);
        i2 = wave_allreduce(i2); i3 = wave_allreduce(i3);
        if (lane < 4) {
            float mine = (lane == 0) ? i0 : (lane == 1) ? i1 : (lane == 2) ? i2 : i3;
            ihx_lds[lr0 + lane]   = mine + bsum;
            wflag_lds[lr0 + lane] = wflg;
        }
        #undef IH_ISSUE
        #undef IH_CONS
    }

    // ------------- recurrence: W_hh re-streamed per step via DMA -------------
    float csum = 0.f, r_halt = 0.f;
    int   n_halt = 0;
    for (int t = 0; t <= MSTEPS; ++t) {
        const float* hsrc = (t == 0) ? h0 : ((t & 1) ? hbuf0 : hbuf1); // h_{t-1} in hbuf[(t-1)&1]
        ((float4*)h_lds)[tid] = ((const float4*)hsrc)[tid];
        __syncthreads();   // h_lds ready; drains vmcnt to 0

        float a0 = 0.f, a1 = 0.f, a2 = 0.f, a3 = 0.f;
        {
            #define HH_ISSUE(c_) do {                                          \
                const float* g = W_hh + (size_t)(rbase + ((c_) >> 1)) * HID    \
                               + ((c_) & 1) * 1024 + 4 * lane;                 \
                float* lb = &stage[wave][(c_) & 1][0];                         \
                dma16(g,       lb);       dma16(g + 256, lb + 256);            \
                dma16(g + 512, lb + 512); dma16(g + 768, lb + 768);            \
            } while (0)
            #define HH_CONS(c_) do {                                           \
                const float4* wb = (const float4*)&stage[wave][(c_) & 1][0];   \
                const float4* hb = (const float4*)(h_lds + ((c_) & 1) * 1024); \
                float s = 0.f;                                                 \
                _Pragma("unroll")                                              \
                for (int m = 0; m < 4; ++m) {                                  \
                    float4 w4 = wb[lane + 64 * m];                             \
                    float4 h4 = hb[lane + 64 * m];                             \
                    s += w4.x*h4.x + w4.y*h4.y + w4.z*h4.z + w4.w*h4.w;        \
                }                                                              \
                if      (((c_) >> 1) == 0) a0 += s;                            \
                else if (((c_) >> 1) == 1) a1 += s;                            \
                else if (((c_) >> 1) == 2) a2 += s;                            \
                else                       a3 += s;                            \
            } while (0)
            HH_ISSUE(0); HH_ISSUE(1);
            WAITV(4); HH_CONS(0); WAITLGKM(); HH_ISSUE(2);
            WAITV(4); HH_CONS(1); WAITLGKM(); HH_ISSUE(3);
            WAITV(4); HH_CONS(2); WAITLGKM(); HH_ISSUE(4);
            WAITV(4); HH_CONS(3); WAITLGKM(); HH_ISSUE(5);
            WAITV(4); HH_CONS(4); WAITLGKM(); HH_ISSUE(6);
            WAITV(4); HH_CONS(5); WAITLGKM(); HH_ISSUE(7);
            WAITV(4); HH_CONS(6);
            WAITV(0); HH_CONS(7);
            #undef HH_ISSUE
            #undef HH_CONS
        }
        a0 = wave_allreduce(a0); a1 = wave_allreduce(a1);
        a2 = wave_allreduce(a2); a3 = wave_allreduce(a3);
        if (lane < 4) {
            float mine = (lane == 0) ? a0 : (lane == 1) ? a1 : (lane == 2) ? a2 : a3;
            float bb = ihx_lds[lr0 + lane];
            if (t == 0) bb += wflag_lds[lr0 + lane];
            gate_lds[lr0 + lane] = bb + mine;
        }
        __syncthreads();

        float part = 0.f;
        float* hdst = (t & 1) ? hbuf1 : hbuf0;   // h_t lives in hbuf[t&1]
        if (tid < JPB) {
            float iv = gate_lds[0 * JPB + tid];
            float fv = gate_lds[1 * JPB + tid];
            float gv = gate_lds[2 * JPB + tid];
            float ov = gate_lds[3 * JPB + tid];
            iv = 1.f / (1.f + expf(-iv));
            fv = 1.f / (1.f + expf(-fv));
            gv = tanhf(gv);
            ov = 1.f / (1.f + expf(-ov));
            c_reg = fv * c_reg + iv * gv;
            h_reg = ov * tanhf(c_reg);
            hdst[j_own] = h_reg;
            part = h_reg * w_halt[j_own];
        }
        part += __shfl_down(part, 4, 64);
        part += __shfl_down(part, 2, 64);
        part += __shfl_down(part, 1, 64);

        float dotv;
        SYNC_ROUND(t + 1, part, dotv);

        float p = 1.f / (1.f + expf(-(dotv + bh)));
        float prev = csum;
        csum += p;
        bool halt_now = (csum >= 1.f - 0.01f) || (t == MSTEPS);
        float wt = halt_now ? (1.f - prev) : p;
        if (tid < JPB) { hbar += wt * h_reg; cbar += wt * c_reg; }
        if (halt_now) { n_halt = t; r_halt = 1.f - prev; break; }  // uniform
    }

    // ------------- epilogue -------------
    if (tid < JPB) {
        out[OUTS + j_own]       = hbar;   // h_out
        out[OUTS + HID + j_own] = cbar;   // c_out
        hbar_g[j_own] = hbar;
    }
    if (b == 0 && tid == 0) out[OUTS + 2 * HID] = (float)(n_halt + 1) + r_halt;

    float dummy;
    SYNC_ROUND(n_halt + 2, 0.f, dummy);
    (void)dummy;

    float* hbar_lds = &stage[0][0][0];   // reuse stream LDS (streams drained)
    ((float4*)hbar_lds)[tid] = ((const float4*)hbar_g)[tid];
    __syncthreads();

    // output = W_out @ hbar + b_out : 4 rows/block, half-row per wave
    {
        const int row  = b * 4 + (wave & 3);
        const int half = wave >> 2;
        const float4* wrow = (const float4*)(W_out + (size_t)row * HID) + half * 256;
        const float4* hv   = (const float4*)hbar_lds + half * 256;
        float acc = 0.f;
        #pragma unroll
        for (int m = 0; m < 4; ++m) {
            float4 w4 = wrow[lane + 64 * m];
            float4 h4 = hv[lane + 64 * m];
            acc += w4.x * h4.x + w4.y * h4.y + w4.z * h4.z + w4.w * h4.w;
        }
        acc = wave_allreduce(acc);
        if (lane == 0) psum[wave] = acc;
    }
    __syncthreads();
    if (tid < 4) {
        int row = b * 4 + tid;
        out[row] = psum[tid] + psum[tid + 4] + b_out[row];
    }
    #undef SYNC_ROUND
}

extern "C" void kernel_launch(void* const* d_in, const int* in_sizes, int n_in,
                              void* d_out, int out_size, void* d_ws, size_t ws_size,
                              hipStream_t stream) {
    const float* x      = (const float*)d_in[0];
    const float* h0     = (const float*)d_in[1];
    const float* c0     = (const float*)d_in[2];
    const float* W_ih   = (const float*)d_in[3];
    const float* b_ih   = (const float*)d_in[4];
    const float* W_hh   = (const float*)d_in[5];
    const float* b_hh   = (const float*)d_in[6];
    const float* w_halt = (const float*)d_in[7];
    const float* b_halt = (const float*)d_in[8];
    const float* W_out  = (const float*)d_in[9];
    const float* b_out  = (const float*)d_in[10];
    float* out = (float*)d_out;
    float* ws  = (float*)d_ws;

    // Zero arrive slots + mailboxes (ws is poisoned 0xAA by the harness).
    hipMemsetAsync(d_ws, 0, 32768, stream);

    alstm_kernel<<<dim3(NBLK), dim3(NTHR), 0, stream>>>(
        x, h0, c0, W_ih, b_ih, W_hh, b_hh, w_halt, b_halt, W_out, b_out,
        out, ws);
}

// Round 13
// 183.765 us; speedup vs baseline: 1.0360x; 1.0360x over previous
//
#include <hip/hip_runtime.h>

// ALSTM: adaptive-computation-time LSTM — multi-kernel decomposition.
//  - sum(w)==1  =>  output = (w@H)@W_out^T + b_out ; only hbar/cbar needed.
//  - halting is data-dependent-exact: steps after halt have w==0 (bench
//    input halts at t=1; K5 is the correctness fallback for t>=2).
// R12 post-mortem: persistent 256-block kernel caps at 8-16 waves/CU =>
// ~1-2MB in flight => ~1.5 TB/s streaming wall regardless of load path.
// R13: full-occupancy stream kernels (8192 waves for the 100MB one-shot),
// sequencing via kernel boundaries instead of software grid barriers.

#define HID    2048
#define INS    1024
#define OUTS   1024
#define MSTEPS 100
#define EPS1   (1.0f - 0.01f)

typedef unsigned long long u64;
typedef unsigned int u32;

// ---- ws float layout ----
#define WS_CTRL   0                    // [0]=done0(u32) [1]=alldone(u32) [2]=p0 [3]=csum1
#define WS_IHX    16                   // [8192]
#define WS_G      (16 + 8192)          // [8192] gate pre-activations
#define WS_HCUR   (16 + 16384)         // [2048]
#define WS_CCUR   (WS_HCUR + 2048)
#define WS_HBAR   (WS_HCUR + 4096)
#define WS_CBAR   (WS_HCUR + 6144)
#define WS_HSPARE (WS_HCUR + 8192)     // [2048] K5 double buffer
#define WS_ARR    (WS_HCUR + 10240)    // arrive slots 256x16
#define WS_MAIL   (WS_ARR + 4096)      // mailboxes  256x16
#define SLOTF     16

__device__ __forceinline__ float wave_allreduce(float v) {
    #pragma unroll
    for (int off = 32; off > 0; off >>= 1)
        v += __shfl_xor(v, off, 64);
    return v;
}
__device__ __forceinline__ float sigm(float v) { return 1.f / (1.f + expf(-v)); }

__device__ __forceinline__ u64 pack_tag(unsigned tag, float v) {
    return ((u64)tag << 32) | (u64)__float_as_uint(v);
}
__device__ __forceinline__ u64 aload(const u64* p) {
    return __hip_atomic_load(p, __ATOMIC_RELAXED, __HIP_MEMORY_SCOPE_AGENT);
}
__device__ __forceinline__ void astore(u64* p, u64 v) {
    __hip_atomic_store(p, v, __ATOMIC_RELAXED, __HIP_MEMORY_SCOPE_AGENT);
}

// ---------- K1: ihx + step-0 gates. grid 2048 x 256 (wave per gate-row) ----------
__global__ void k1_gates0(const float* __restrict__ x, const float* __restrict__ h0,
                          const float* __restrict__ W_ih, const float* __restrict__ b_ih,
                          const float* __restrict__ W_hh, const float* __restrict__ b_hh,
                          float* __restrict__ ws)
{
    __shared__ __align__(16) float xh[INS + HID];
    const int tid = threadIdx.x, wave = tid >> 6, lane = tid & 63;
    if (tid < 256) ((float4*)xh)[tid] = ((const float4*)x)[tid];
    ((float4*)(xh + INS))[tid]       = ((const float4*)h0)[tid];
    ((float4*)(xh + INS))[tid + 256] = ((const float4*)h0)[tid + 256];
    __syncthreads();

    const int r = blockIdx.x * 4 + wave;
    // W_ih[r,1:] . x  (unaligned row: peel scheme, verified R7/R11)
    const float* wrow = W_ih + (size_t)r * (INS + 1) + 1;
    const int p0 = (4 - ((r + 1) & 3)) & 3;
    const float4* wv = (const float4*)(wrow + p0);
    float acc = 0.f;
    #pragma unroll
    for (int ii = 0; ii < 4; ++ii) {
        int i = lane + 64 * ii;
        if (i < 255) {
            float4 w4 = wv[i]; int k = p0 + 4 * i;
            acc += w4.x * xh[k] + w4.y * xh[k + 1] + w4.z * xh[k + 2] + w4.w * xh[k + 3];
        }
    }
    if (lane < 4) {
        int e = (lane < p0) ? lane : 1020 + lane;
        acc += wrow[e] * xh[e];
    }
    // W_hh[r] . h0
    const float4* wh = (const float4*)(W_hh + (size_t)r * HID);
    const float4* hv = (const float4*)(xh + INS);
    float acch = 0.f;
    #pragma unroll
    for (int m = 0; m < 8; ++m) {
        float4 w4 = wh[lane + 64 * m], h4 = hv[lane + 64 * m];
        acch += w4.x * h4.x + w4.y * h4.y + w4.z * h4.z + w4.w * h4.w;
    }
    acc  = wave_allreduce(acc);
    acch = wave_allreduce(acch);
    if (lane == 0) {
        float ihx = acc + b_ih[r] + b_hh[r];
        ws[WS_IHX + r] = ihx;
        ws[WS_G + r]   = ihx + W_ih[(size_t)r * (INS + 1)] + acch;  // flag=1 at t=0
    }
}

// ---------- K2: cell + halt for t=0. 1 block x 512 ----------
__global__ void k2_cell0(const float* __restrict__ c0, const float* __restrict__ w_halt,
                         const float* __restrict__ b_halt, float* __restrict__ out,
                         float* __restrict__ ws)
{
    __shared__ float red[8];
    __shared__ float sh_w;
    __shared__ int   sh_halt;
    const int tid = threadIdx.x, wave = tid >> 6, lane = tid & 63;
    float hv[4], cv[4], part = 0.f;
    #pragma unroll
    for (int u = 0; u < 4; ++u) {
        int j = tid + 512 * u;
        float iv = sigm(ws[WS_G + 0 * HID + j]);
        float fv = sigm(ws[WS_G + 1 * HID + j]);
        float gv = tanhf(ws[WS_G + 2 * HID + j]);
        float ov = sigm(ws[WS_G + 3 * HID + j]);
        float c = fv * c0[j] + iv * gv;
        float h = ov * tanhf(c);
        cv[u] = c; hv[u] = h;
        ws[WS_HCUR + j] = h; ws[WS_CCUR + j] = c;
        part += h * w_halt[j];
    }
    part = wave_allreduce(part);
    if (lane == 0) red[wave] = part;
    __syncthreads();
    if (tid == 0) {
        float d = red[0] + red[1] + red[2] + red[3] + red[4] + red[5] + red[6] + red[7];
        float p0 = sigm(d + b_halt[0]);
        int halted = (p0 >= EPS1);
        ws[WS_CTRL + 2] = p0;
        ((u32*)ws)[0] = halted;
        if (halted) { ((u32*)ws)[1] = 1; out[OUTS + 2 * HID] = 2.0f; }  // n=0, r=1
        sh_w = halted ? 1.0f : p0;
        sh_halt = halted;
    }
    __syncthreads();
    float w0 = sh_w; int hl = sh_halt;
    #pragma unroll
    for (int u = 0; u < 4; ++u) {
        int j = tid + 512 * u;
        float hb = w0 * hv[u], cb = w0 * cv[u];
        ws[WS_HBAR + j] = hb; ws[WS_CBAR + j] = cb;
        if (hl) { out[OUTS + j] = hb; out[OUTS + HID + j] = cb; }
    }
}

// ---------- K3: step-1 gates. grid 2048 x 256 ----------
__global__ void k3_gates1(const float* __restrict__ W_hh, float* __restrict__ ws)
{
    if (((const u32*)ws)[0]) return;   // halted at t=0
    __shared__ __align__(16) float h_lds[HID];
    const int tid = threadIdx.x, wave = tid >> 6, lane = tid & 63;
    ((float4*)h_lds)[tid]       = ((const float4*)(ws + WS_HCUR))[tid];
    ((float4*)h_lds)[tid + 256] = ((const float4*)(ws + WS_HCUR))[tid + 256];
    __syncthreads();
    const int r = blockIdx.x * 4 + wave;
    const float4* wh = (const float4*)(W_hh + (size_t)r * HID);
    const float4* hv = (const float4*)h_lds;
    float acc = 0.f;
    #pragma unroll
    for (int m = 0; m < 8; ++m) {
        float4 w4 = wh[lane + 64 * m], h4 = hv[lane + 64 * m];
        acc += w4.x * h4.x + w4.y * h4.y + w4.z * h4.z + w4.w * h4.w;
    }
    acc = wave_allreduce(acc);
    if (lane == 0) ws[WS_G + r] = ws[WS_IHX + r] + acc;
}

// ---------- K4: cell + halt for t=1 (+finalize if halted). 1 block x 512 ----------
__global__ void k4_cell1(const float* __restrict__ w_halt, const float* __restrict__ b_halt,
                         float* __restrict__ out, float* __restrict__ ws)
{
    if (((const u32*)ws)[0]) return;
    __shared__ float red[8];
    __shared__ float sh_w;
    __shared__ int   sh_halt;
    const int tid = threadIdx.x, wave = tid >> 6, lane = tid & 63;
    float hv[4], cv[4], part = 0.f;
    #pragma unroll
    for (int u = 0; u < 4; ++u) {
        int j = tid + 512 * u;
        float iv = sigm(ws[WS_G + 0 * HID + j]);
        float fv = sigm(ws[WS_G + 1 * HID + j]);
        float gv = tanhf(ws[WS_G + 2 * HID + j]);
        float ov = sigm(ws[WS_G + 3 * HID + j]);
        float c = fv * ws[WS_CCUR + j] + iv * gv;
        float h = ov * tanhf(c);
        cv[u] = c; hv[u] = h;
        ws[WS_HCUR + j] = h; ws[WS_CCUR + j] = c;
        part += h * w_halt[j];
    }
    part = wave_allreduce(part);
    if (lane == 0) red[wave] = part;
    __syncthreads();
    if (tid == 0) {
        float d = red[0] + red[1] + red[2] + red[3] + red[4] + red[5] + red[6] + red[7];
        float p1 = sigm(d + b_halt[0]);
        float p0 = ws[WS_CTRL + 2];
        float csum = p0 + p1;
        int halted = (csum >= EPS1);
        if (halted) {
            float r_ = 1.f - p0;                 // 1 - (csum[n]-p[n])
            ((u32*)ws)[1] = 1;
            out[OUTS + 2 * HID] = 2.0f + r_;     // n=1 -> n+1+r
            sh_w = r_;
        } else {
            ws[WS_CTRL + 3] = csum;
            sh_w = p1;
        }
        sh_halt = halted;
    }
    __syncthreads();
    float w1 = sh_w; int hl = sh_halt;
    #pragma unroll
    for (int u = 0; u < 4; ++u) {
        int j = tid + 512 * u;
        float hb = ws[WS_HBAR + j] + w1 * hv[u];
        float cb = ws[WS_CBAR + j] + w1 * cv[u];
        ws[WS_HBAR + j] = hb; ws[WS_CBAR + j] = cb;
        if (hl) { out[OUTS + j] = hb; out[OUTS + HID + j] = cb; }
    }
}

// ---------- K5: fallback for t>=2 (no-op when already halted). 256 x 512 ----------
__global__ __launch_bounds__(512) void k5_tail(
    const float* __restrict__ W_hh, const float* __restrict__ w_halt,
    const float* __restrict__ b_halt, float* __restrict__ out,
    float* __restrict__ ws)
{
    if (((const u32*)ws)[1]) return;   // alldone (bench path exits here)
    const int b = blockIdx.x, tid = threadIdx.x, wave = tid >> 6, lane = tid & 63;
    float* arrive = ws + WS_ARR;
    float* mail   = ws + WS_MAIL;
    __shared__ __align__(16) float h_lds[HID];
    __shared__ float gate_lds[32];
    __shared__ float red_lds[4];
    __shared__ float bcast_lds;
    const float bh = b_halt[0];
    const int j_own = b * 8 + tid;          // valid when tid < 8
    const int lr0 = 4 * wave;
    const int rbase = (lr0 >> 3) * HID + b * 8 + (lr0 & 7);

    float c_reg = 0.f, h_reg = 0.f, hbar = 0.f, cbar = 0.f, csum = 0.f;
    if (tid < 8) {
        c_reg = ws[WS_CCUR + j_own];
        hbar  = ws[WS_HBAR + j_own];
        cbar  = ws[WS_CBAR + j_own];
    }
    csum = ws[WS_CTRL + 3];
    float r_halt = 0.f; int n_halt = MSTEPS;

    for (int t = 2; t <= MSTEPS; ++t) {
        const float* hsrc = ws + ((t & 1) ? WS_HSPARE : WS_HCUR);   // t=2 reads HCUR
        float*       hdst = ws + ((t & 1) ? WS_HCUR : WS_HSPARE);
        ((float4*)h_lds)[tid] = ((const float4*)hsrc)[tid];
        __syncthreads();
        float a[4] = {0.f, 0.f, 0.f, 0.f};
        #pragma unroll
        for (int rr = 0; rr < 4; ++rr) {
            const float4* wh = (const float4*)(W_hh + (size_t)(rbase + rr) * HID);
            const float4* hv = (const float4*)h_lds;
            float s = 0.f;
            #pragma unroll
            for (int m = 0; m < 8; ++m) {
                float4 w4 = wh[lane + 64 * m], h4 = hv[lane + 64 * m];
                s += w4.x * h4.x + w4.y * h4.y + w4.z * h4.z + w4.w * h4.w;
            }
            a[rr] = wave_allreduce(s);
        }
        if (lane < 4)
            gate_lds[lr0 + lane] = ws[WS_IHX + ((lr0 + lane) >> 3) * HID + b * 8 + ((lr0 + lane) & 7)]
                                 + a[lane];
        __syncthreads();

        float part = 0.f;
        if (tid < 8) {
            float iv = sigm(gate_lds[0 * 8 + tid]);
            float fv = sigm(gate_lds[1 * 8 + tid]);
            float gv = tanhf(gate_lds[2 * 8 + tid]);
            float ov = sigm(gate_lds[3 * 8 + tid]);
            c_reg = fv * c_reg + iv * gv;
            h_reg = ov * tanhf(c_reg);
            hdst[j_own] = h_reg;
            part = h_reg * w_halt[j_own];
        }
        part += __shfl_down(part, 4, 64);
        part += __shfl_down(part, 2, 64);
        part += __shfl_down(part, 1, 64);

        // mailbox sync fused with halt-dot reduce (R6 mechanism)
        if (tid == 0) {
            __threadfence();
            astore((u64*)(arrive + SLOTF * b), pack_tag(t, part));
        }
        if (b == 0) {
            float pf = 0.f;
            if (tid < 256) {
                u64 v;
                do { v = aload((u64*)(arrive + SLOTF * tid)); }
                while ((unsigned)(v >> 32) != (unsigned)t);
                pf = __uint_as_float((unsigned)v);
            }
            float s = wave_allreduce(pf);
            if (lane == 0 && wave < 4) red_lds[wave] = s;
            __syncthreads();
            if (tid == 0) bcast_lds = red_lds[0] + red_lds[1] + red_lds[2] + red_lds[3];
            __syncthreads();
            if (tid < 256)
                astore((u64*)(mail + SLOTF * tid), pack_tag(t, bcast_lds));
        }
        if (tid == 0) {
            u64 v;
            do { v = aload((u64*)(mail + SLOTF * b)); }
            while ((unsigned)(v >> 32) != (unsigned)t);
            bcast_lds = __uint_as_float((unsigned)v);
            __threadfence();
        }
        __syncthreads();
        float dotv = bcast_lds;

        float p = sigm(dotv + bh);
        float prev = csum;
        csum += p;
        bool halt_now = (csum >= EPS1) || (t == MSTEPS);
        float wt = halt_now ? (1.f - prev) : p;
        if (tid < 8) { hbar += wt * h_reg; cbar += wt * c_reg; }
        if (halt_now) { n_halt = t; r_halt = 1.f - prev; break; }
        __syncthreads();   // h_lds/gate reuse guard
    }

    if (tid < 8) {
        ws[WS_HBAR + j_own] = hbar;
        ws[WS_CBAR + j_own] = cbar;
        out[OUTS + j_own]       = hbar;
        out[OUTS + HID + j_own] = cbar;
    }
    if (b == 0 && tid == 0) out[OUTS + 2 * HID] = (float)(n_halt + 1) + r_halt;
}

// ---------- K6: output gemv. 256 x 512 ----------
__global__ __launch_bounds__(512) void k6_out(
    const float* __restrict__ W_out, const float* __restrict__ b_out,
    float* __restrict__ out, const float* __restrict__ ws)
{
    __shared__ __align__(16) float h_lds[HID];
    __shared__ float psum[8];
    const int tid = threadIdx.x, wave = tid >> 6, lane = tid & 63;
    ((float4*)h_lds)[tid] = ((const float4*)(ws + WS_HBAR))[tid];
    __syncthreads();
    const int row  = blockIdx.x * 4 + (wave & 3);
    const int half = wave >> 2;
    const float4* wr = (const float4*)(W_out + (size_t)row * HID) + half * 256;
    const float4* hv = (const float4*)h_lds + half * 256;
    float acc = 0.f;
    #pragma unroll
    for (int m = 0; m < 4; ++m) {
        float4 w4 = wr[lane + 64 * m], h4 = hv[lane + 64 * m];
        acc += w4.x * h4.x + w4.y * h4.y + w4.z * h4.z + w4.w * h4.w;
    }
    acc = wave_allreduce(acc);
    if (lane == 0) psum[wave] = acc;
    __syncthreads();
    if (tid < 4) {
        int r = blockIdx.x * 4 + tid;
        out[r] = psum[tid] + psum[tid + 4] + b_out[r];
    }
}

extern "C" void kernel_launch(void* const* d_in, const int* in_sizes, int n_in,
                              void* d_out, int out_size, void* d_ws, size_t ws_size,
                              hipStream_t stream) {
    const float* x      = (const float*)d_in[0];
    const float* h0     = (const float*)d_in[1];
    const float* c0     = (const float*)d_in[2];
    const float* W_ih   = (const float*)d_in[3];
    const float* b_ih   = (const float*)d_in[4];
    const float* W_hh   = (const float*)d_in[5];
    const float* b_hh   = (const float*)d_in[6];
    const float* w_halt = (const float*)d_in[7];
    const float* b_halt = (const float*)d_in[8];
    const float* W_out  = (const float*)d_in[9];
    const float* b_out  = (const float*)d_in[10];
    float* out = (float*)d_out;
    float* ws  = (float*)d_ws;

    // Zero control block + mailbox region (ws poisoned 0xAA each replay).
    hipMemsetAsync(ws, 0, 64, stream);
    hipMemsetAsync(ws + WS_ARR, 0, 8192 * sizeof(float), stream);

    k1_gates0<<<dim3(2048), dim3(256), 0, stream>>>(x, h0, W_ih, b_ih, W_hh, b_hh, ws);
    k2_cell0 <<<dim3(1),    dim3(512), 0, stream>>>(c0, w_halt, b_halt, out, ws);
    k3_gates1<<<dim3(2048), dim3(256), 0, stream>>>(W_hh, ws);
    k4_cell1 <<<dim3(1),    dim3(512), 0, stream>>>(w_halt, b_halt, out, ws);
    k5_tail  <<<dim3(256),  dim3(512), 0, stream>>>(W_hh, w_halt, b_halt, out, ws);
    k6_out   <<<dim3(256),  dim3(512), 0, stream>>>(W_out, b_out, out, ws);
}